// Round 6
// baseline (341.978 us; speedup 1.0000x reference)
//
#include <hip/hip_runtime.h>
#include <math.h>
#include <stdint.h>

#define D_    2048
#define BLK   256
#define KSEL  64
#define NBIN  512    // bin width 1/64 on |z|
#define B0    96     // gate: only |z| >= 1.5 enters the histogram (w/ fallback)
#define CAP   128    // max boundary candidates per select
#define WSLICE 1824  // dwords of LDS per wave

typedef float v2f __attribute__((ext_vector_type(2)));

// same-wave LDS phase fence: completes all outstanding DS ops + compiler fence
#define FENCE() asm volatile("s_waitcnt lgkmcnt(0)" ::: "memory")

// ---------- exact-path helpers (must match np/XLA rounding) ----------
__device__ __forceinline__ float tanh_xla(float x) {
    const float kMax = 7.90531110763549805f;
    float xc = fminf(fmaxf(x, -kMax), kMax);
    float x2 = __fmul_rn(xc, xc);
    float p = -2.76076847742355e-16f;
    p = __fadd_rn(__fmul_rn(p, x2), 2.00018790482477e-13f);
    p = __fadd_rn(__fmul_rn(p, x2), -8.60467152213735e-11f);
    p = __fadd_rn(__fmul_rn(p, x2), 5.12229709037114e-08f);
    p = __fadd_rn(__fmul_rn(p, x2), 1.48572235717979e-05f);
    p = __fadd_rn(__fmul_rn(p, x2), 6.37261928875436e-04f);
    p = __fadd_rn(__fmul_rn(p, x2), 4.89352455891786e-03f);
    float num = __fmul_rn(xc, p);
    float q = 1.19825839466702e-06f;
    q = __fadd_rn(__fmul_rn(q, x2), 1.18534705686654e-04f);
    q = __fadd_rn(__fmul_rn(q, x2), 2.26843463243900e-03f);
    q = __fadd_rn(__fmul_rn(q, x2), 4.89352518554385e-03f);
    float r = __fdiv_rn(num, q);
    return (fabsf(x) < 0.0004f) ? x : r;
}

__device__ __forceinline__ float gelu_exact(float xx) {
    float a = __fmul_rn(0.044715f, xx);
    a = __fmul_rn(a, xx);
    a = __fmul_rn(a, xx);
    float inner = __fadd_rn(xx, a);
    float tg = tanh_xla(__fmul_rn(0.7978845608028654f, inner));
    return __fmul_rn(__fmul_rn(0.5f, xx), __fadd_rn(1.0f, tg));
}

// ---------- fast-path helpers (loose tolerance) ----------
__device__ __forceinline__ float tanh_fast(float y) {
    float e = __builtin_amdgcn_exp2f(y * 2.8853900817779268f);
    return 1.0f - 2.0f * __builtin_amdgcn_rcpf(1.0f + e);
}

// ---------- pre-kernel: denominators + ||dir||^2 + scalar params ----------
__global__ __launch_bounds__(BLK) void prep_kernel(
    const float* __restrict__ m_in, const float* __restrict__ q_in,
    const float* __restrict__ m_out, const float* __restrict__ q_out,
    const float* __restrict__ dirv,
    const float* __restrict__ p_log_tau,
    const float* __restrict__ p_log_beta,
    const float* __restrict__ p_log_gamma,
    float* __restrict__ wsp)
{
    __shared__ float spart[4];
    const int t = threadIdx.x;
    const int c = blockIdx.x * BLK + t;
    if (c < D_) {
        float mi = m_in[c];
        float vi = fmaxf(__fsub_rn(q_in[c], __fmul_rn(mi, mi)), 1e-4f);
        float di = __fadd_rn(__fsqrt_rn(vi), 1e-5f);
        wsp[c]        = di;                       // den_in
        wsp[D_ + c]   = __fdiv_rn(1.0f, di);      // inv_in
        float mo = m_out[c];
        float vo = fmaxf(__fsub_rn(q_out[c], __fmul_rn(mo, mo)), 1e-4f);
        float dd = __fadd_rn(__fsqrt_rn(vo), 1e-5f);
        wsp[2 * D_ + c] = dd;                     // den_out
        wsp[3 * D_ + c] = __fdiv_rn(1.0f, dd);    // inv_out
    }
    if (blockIdx.x == 0) {
        float acc = 0.f;
        #pragma unroll
        for (int k = 0; k < D_ / BLK; ++k) {
            float v = dirv[t + k * BLK];
            acc = fmaf(v, v, acc);
        }
        #pragma unroll
        for (int off = 32; off > 0; off >>= 1) acc += __shfl_xor(acc, off);
        if ((t & 63) == 0) spart[t >> 6] = acc;
        __syncthreads();
        if (t == 0) {
            wsp[4 * D_ + 0] = spart[0] + spart[1] + spart[2] + spart[3]; // ||dir||^2
            wsp[4 * D_ + 1] = expf(p_log_tau[0]);                        // tau
            wsp[4 * D_ + 2] = log1pf(expf(p_log_beta[0]));               // beta
            wsp[4 * D_ + 3] = log1pf(expf(p_log_gamma[0]));              // gamma
        }
    }
}

// per-wave suffix scan + boundary find over both 512-bin hists
__device__ __forceinline__ void scan_both(uint32_t* whist, uint32_t* scr, int lane)
{
    #pragma unroll
    for (int h2 = 0; h2 < 2; ++h2) {
        uint32_t* hp = whist + h2 * NBIN;
        uint32_t h[8];
        *(uint4*)&h[0] = *(const uint4*)&hp[lane * 8 + 0];
        *(uint4*)&h[4] = *(const uint4*)&hp[lane * 8 + 4];
        uint32_t tot = 0;
        #pragma unroll
        for (int k = 0; k < 8; ++k) tot += h[k];
        uint32_t S = tot;
        #pragma unroll
        for (int d = 1; d < 64; d <<= 1) {
            uint32_t o = __shfl_down(S, d, 64);
            S += (lane + d < 64) ? o : 0u;
        }
        uint32_t run = S - tot;   // suffix strictly after this lane's bins
        #pragma unroll
        for (int k = 7; k >= 0; --k) {
            uint32_t prev = run;
            run += h[k];
            if (run >= (uint32_t)KSEL && prev < (uint32_t)KSEL) {
                scr[2 * h2 + 0] = (uint32_t)(lane * 8 + k);  // B
                scr[2 * h2 + 1] = prev;                      // G (count above B)
            }
        }
    }
}

// ---------- main kernel: one WAVE per row, zero barriers ----------
__global__ __launch_bounds__(BLK, 4) void gelu205_kernel(
    const float* __restrict__ x,
    const float* __restrict__ ema_mean,
    const float* __restrict__ ema_out_mean,
    const float* __restrict__ ema_out_dir,
    const float* __restrict__ wsp,
    float* __restrict__ out,
    int nrows)
{
    __shared__ uint32_t lds[4 * WSLICE];

    const int t = threadIdx.x;
    const int lane = t & 63, wid = t >> 6;
    const int row = blockIdx.x * 4 + wid;
    if (row >= nrows) return;

    uint32_t* wl    = lds + wid * WSLICE;
    uint32_t* whist = wl;                     // 2*512
    uint32_t* cbI   = wl + 1024;
    uint32_t* ciI   = wl + 1024 + CAP;
    uint32_t* cfI   = wl + 1024 + 2 * CAP;
    uint32_t* cbO   = wl + 1024 + 3 * CAP;
    uint32_t* ciO   = wl + 1024 + 4 * CAP;
    uint32_t* cfO   = wl + 1024 + 5 * CAP;
    uint32_t* scr   = wl + 1024 + 6 * CAP;    // [0]Bi [1]Gi [2]Bo [3]Go [4]ncI [5]ncO

    const float* xr = x + (size_t)row * D_;
    float* outr = out + (size_t)row * D_;

    const float* den_in  = wsp;
    const float* inv_in  = wsp + D_;
    const float* den_out = wsp + 2 * D_;
    const float* inv_out = wsp + 3 * D_;
    const float dd_row = wsp[4 * D_ + 0];
    const float tau    = wsp[4 * D_ + 1];
    const float beta   = wsp[4 * D_ + 2];
    const float gamma  = wsp[4 * D_ + 3];

    // zero hist slice (16 dwords/lane) + scratch
    {
        uint4 z4 = make_uint4(0u, 0u, 0u, 0u);
        *(uint4*)&whist[lane * 16 + 0]  = z4;
        *(uint4*)&whist[lane * 16 + 4]  = z4;
        *(uint4*)&whist[lane * 16 + 8]  = z4;
        *(uint4*)&whist[lane * 16 + 12] = z4;
    }
    if (lane < 6) scr[lane] = (lane == 0 || lane == 2) ? 0xffffffffu : 0u;

    // ---- elementwise pass: 32 elems/lane ----
    float ov[32];
    uint32_t bp[32];                 // bin_in | bin_out<<16
    v2f acc_oo = {0.f, 0.f}, acc_od = {0.f, 0.f};

    #pragma unroll
    for (int k = 0; k < 8; ++k) {
        const int base = (k << 8) + (lane << 2);
        float4 x4  = *(const float4*)(xr + base);
        float4 m4  = *(const float4*)(ema_mean + base);
        float4 i4  = *(const float4*)(inv_in + base);
        float4 mo4 = *(const float4*)(ema_out_mean + base);
        float4 io4 = *(const float4*)(inv_out + base);
        float4 d4  = *(const float4*)(ema_out_dir + base);
        const v2f* xp2  = (const v2f*)&x4;
        const v2f* mp2  = (const v2f*)&m4;
        const v2f* ip2  = (const v2f*)&i4;
        const v2f* mop2 = (const v2f*)&mo4;
        const v2f* iop2 = (const v2f*)&io4;
        const v2f* dp2  = (const v2f*)&d4;
        #pragma unroll
        for (int p = 0; p < 2; ++p) {
            const int j = k * 4 + p * 2;
            v2f xx = xp2[p];
            // fast gelu: x * sigmoid(1.5957691*(x+0.044715x^3)) via exp2
            v2f x2 = xx * xx;
            v2f ax = xx * 0.044715f;
            v2f inner = __builtin_elementwise_fma(ax, x2, xx);
            v2f ea = inner * -2.3022269136469443f;
            v2f ev; ev.x = __builtin_amdgcn_exp2f(ea.x);
            ev.y = __builtin_amdgcn_exp2f(ea.y);
            v2f dn = ev + 1.0f;
            v2f sgm; sgm.x = __builtin_amdgcn_rcpf(dn.x);
            sgm.y = __builtin_amdgcn_rcpf(dn.y);
            v2f o2 = xx * sgm;
            ov[j] = o2.x; ov[j + 1] = o2.y;
            v2f zi2 = (xx - mp2[p]) * ip2[p];
            v2f zo2 = (o2 - mop2[p]) * iop2[p];
            int bi0 = (int)fminf(fabsf(zi2.x) * 64.0f, 511.0f);
            int bi1 = (int)fminf(fabsf(zi2.y) * 64.0f, 511.0f);
            int bo0 = (int)fminf(fabsf(zo2.x) * 64.0f, 511.0f);
            int bo1 = (int)fminf(fabsf(zo2.y) * 64.0f, 511.0f);
            bp[j]     = (uint32_t)bi0 | ((uint32_t)bo0 << 16);
            bp[j + 1] = (uint32_t)bi1 | ((uint32_t)bo1 << 16);
            acc_oo = __builtin_elementwise_fma(o2, o2, acc_oo);
            acc_od = __builtin_elementwise_fma(o2, dp2[p], acc_od);
        }
    }

    // ---- cosine gate: pure wave shuffle reduce, all lanes compute gcos ----
    float s_oo = acc_oo.x + acc_oo.y;
    float s_od = acc_od.x + acc_od.y;
    #pragma unroll
    for (int off = 32; off > 0; off >>= 1) {
        s_oo += __shfl_xor(s_oo, off);
        s_od += __shfl_xor(s_od, off);
    }
    float no = fmaxf(sqrtf(s_oo), 1e-12f);
    float nd = fmaxf(sqrtf(dd_row), 1e-12f);
    float cs = fminf(fmaxf(s_od / (no * nd), -1.0f), 1.0f);
    const float gcos = expf(-tau * cs);

    // ---- gated histograms (private per wave; no cross-wave contention) ----
    FENCE();
    #pragma unroll
    for (int j = 0; j < 32; ++j) {
        uint32_t bi = bp[j] & 0xffffu, bo = bp[j] >> 16;
        if (bi >= (uint32_t)B0) atomicAdd(&whist[bi], 1u);
        if (bo >= (uint32_t)B0) atomicAdd(&whist[NBIN + bo], 1u);
    }
    FENCE();
    scan_both(whist, scr, lane);
    FENCE();
    int Bi = (int)scr[0], Bo = (int)scr[2];

    // uniform fallback: fewer than KSEL above the gate -> complete the hist
    if (Bi < 0 || Bo < 0) {
        #pragma unroll
        for (int j = 0; j < 32; ++j) {
            uint32_t bi = bp[j] & 0xffffu, bo = bp[j] >> 16;
            if (Bi < 0 && bi < (uint32_t)B0) atomicAdd(&whist[bi], 1u);
            if (Bo < 0 && bo < (uint32_t)B0) atomicAdd(&whist[NBIN + bo], 1u);
        }
        FENCE();
        scan_both(whist, scr, lane);
        FENCE();
        Bi = (int)scr[0]; Bo = (int)scr[2];
    }

    // ---- boundary-candidate gather via ctz bit-loops; exact recompute ----
    uint32_t eqI = 0u, eqO = 0u;
    #pragma unroll
    for (int j = 0; j < 32; ++j) {
        eqI |= ((bp[j] & 0xffffu) == (uint32_t)Bi) ? (1u << j) : 0u;
        eqO |= ((bp[j] >> 16) == (uint32_t)Bo) ? (1u << j) : 0u;
    }
    uint32_t sAI = ~0u, sBI = ~0u, sAO = ~0u, sBO = ~0u;
    int cntI = 0, cntO = 0;
    {
        uint32_t m = eqI;
        while (__any(m != 0u)) {
            if (m) {
                int j = __builtin_ctz(m); m &= m - 1u;
                int ch = ((j >> 2) << 8) | (lane << 2) | (j & 3);
                float xx = xr[ch];
                float ze = fabsf(__fdiv_rn(__fsub_rn(xx, ema_mean[ch]), den_in[ch]));
                uint32_t sl = atomicAdd(&scr[4], 1u);
                if (sl < CAP) {
                    cbI[sl] = __float_as_uint(ze);
                    ciI[sl] = (uint32_t)ch;
                    if (cntI == 0) sAI = (sl << 5) | (uint32_t)j;
                    else if (cntI == 1) sBI = (sl << 5) | (uint32_t)j;
                    ++cntI;
                }
            }
        }
        m = eqO;
        while (__any(m != 0u)) {
            if (m) {
                int j = __builtin_ctz(m); m &= m - 1u;
                int ch = ((j >> 2) << 8) | (lane << 2) | (j & 3);
                float xx = xr[ch];
                float oe = gelu_exact(xx);
                float ze = fabsf(__fdiv_rn(__fsub_rn(oe, ema_out_mean[ch]), den_out[ch]));
                uint32_t sl = atomicAdd(&scr[5], 1u);
                if (sl < CAP) {
                    cbO[sl] = __float_as_uint(ze);
                    ciO[sl] = (uint32_t)ch;
                    if (cntO == 0) sAO = (sl << 5) | (uint32_t)j;
                    else if (cntO == 1) sBO = (sl << 5) | (uint32_t)j;
                    ++cntO;
                }
            }
        }
    }
    FENCE();

    // ---- exact rank among candidates (value desc, index asc = jax tie rule) ----
    {
        const int ncI = min((int)scr[4], CAP), ncO = min((int)scr[5], CAP);
        const uint32_t needI = (uint32_t)(KSEL - (int)scr[1]);
        const uint32_t needO = (uint32_t)(KSEL - (int)scr[3]);
        #pragma unroll
        for (int rr = 0; rr < 2; ++rr) {
            const int i = lane + rr * 64;
            if (i < ncI) {
                uint32_t ui = cbI[i], di = ciI[i], r = 0;
                for (int jj = 0; jj < ncI; ++jj) {
                    uint32_t uj = cbI[jj];
                    r += (uj > ui || (uj == ui && ciI[jj] < di)) ? 1u : 0u;
                }
                cfI[i] = (r < needI) ? 1u : 0u;
            }
            if (i < ncO) {
                uint32_t ui = cbO[i], di = ciO[i], r = 0;
                for (int jj = 0; jj < ncO; ++jj) {
                    uint32_t uj = cbO[jj];
                    r += (uj > ui || (uj == ui && ciO[jj] < di)) ? 1u : 0u;
                }
                cfO[i] = (r < needO) ? 1u : 0u;
            }
        }
    }
    FENCE();

    // ---- per-lane boundary-selected bitmasks ----
    uint32_t bmI = 0u, bmO = 0u;
    if (sAI != ~0u && cfI[sAI >> 5]) bmI |= 1u << (sAI & 31u);
    if (sBI != ~0u && cfI[sBI >> 5]) bmI |= 1u << (sBI & 31u);
    if (sAO != ~0u && cfO[sAO >> 5]) bmO |= 1u << (sAO & 31u);
    if (sBO != ~0u && cfO[sBO >> 5]) bmO |= 1u << (sBO & 31u);
    const bool ovfI = (cntI > 2), ovfO = (cntO > 2);
    const int ncI2 = min((int)scr[4], CAP), ncO2 = min((int)scr[5], CAP);

    // ---- epilogue: lazy gate + write ----
    #pragma unroll
    for (int k = 0; k < 8; ++k) {
        float4 r4;
        float* rp = (float*)&r4;
        #pragma unroll
        for (int l = 0; l < 4; ++l) {
            const int j = k * 4 + l;
            const uint32_t bi = bp[j] & 0xffffu, bo = bp[j] >> 16;
            bool selI = bi > (uint32_t)Bi;
            if (bi == (uint32_t)Bi) {
                if (!ovfI) selI = (bmI >> j) & 1u;
                else {
                    const uint32_t ch = (uint32_t)((k << 8) | (lane << 2) | l);
                    selI = false;
                    for (int jj = 0; jj < ncI2; ++jj)
                        if (ciI[jj] == ch) { selI = cfI[jj] != 0u; break; }
                }
            }
            bool selO = bo > (uint32_t)Bo;
            if (bo == (uint32_t)Bo) {
                if (!ovfO) selO = (bmO >> j) & 1u;
                else {
                    const uint32_t ch = (uint32_t)((k << 8) | (lane << 2) | l);
                    selO = false;
                    for (int jj = 0; jj < ncO2; ++jj)
                        if (ciO[jj] == ch) { selO = cfO[jj] != 0u; break; }
                }
            }
            float gate = 1.0f;
            if (selI && selO) {
                const int ch = (k << 8) | (lane << 2) | l;
                float xx = xr[ch];
                float zi = (xx - ema_mean[ch]) * inv_in[ch];
                float th = tanh_fast(gamma * zi);
                gate = fminf(fmaxf(fmaf(beta, th, 1.0f), 0.1f), 8.0f);
            }
            rp[l] = ov[j] * gate * gcos;
        }
        *(float4*)(outr + (k << 8) + (lane << 2)) = r4;
    }
}

extern "C" void kernel_launch(void* const* d_in, const int* in_sizes, int n_in,
                              void* d_out, int out_size, void* d_ws, size_t ws_size,
                              hipStream_t stream) {
    const float* x            = (const float*)d_in[0];
    const float* p_log_tau    = (const float*)d_in[2];
    const float* p_log_beta   = (const float*)d_in[3];
    const float* p_log_gamma  = (const float*)d_in[4];
    const float* ema_mean     = (const float*)d_in[5];
    const float* ema_sq       = (const float*)d_in[6];
    const float* ema_out_mean = (const float*)d_in[7];
    const float* ema_out_sq   = (const float*)d_in[8];
    const float* ema_out_dir  = (const float*)d_in[9];
    float* wsp = (float*)d_ws;
    const int rows = in_sizes[0] / D_;

    prep_kernel<<<(D_ + BLK - 1) / BLK, BLK, 0, stream>>>(
        ema_mean, ema_sq, ema_out_mean, ema_out_sq, ema_out_dir,
        p_log_tau, p_log_beta, p_log_gamma, wsp);
    gelu205_kernel<<<(rows + 3) / 4, BLK, 0, stream>>>(
        x, ema_mean, ema_out_mean, ema_out_dir, wsp,
        (float*)d_out, rows);
}

// Round 7
// 122.375 us; speedup vs baseline: 2.7945x; 2.7945x over previous
//
#include <hip/hip_runtime.h>
#include <math.h>
#include <stdint.h>

#define D_    2048
#define BLK   256
#define KSEL  64
#define NBIN  512    // bin width 1/64 on |z|
#define B0    96     // gate: only |z| >= 1.5 enters the histogram (w/ fallback)
#define CAP   128    // max boundary candidates per select

typedef float v2f __attribute__((ext_vector_type(2)));

// ---------- exact-path helpers (must match np/XLA rounding) ----------
__device__ __forceinline__ float tanh_xla(float x) {
    const float kMax = 7.90531110763549805f;
    float xc = fminf(fmaxf(x, -kMax), kMax);
    float x2 = __fmul_rn(xc, xc);
    float p = -2.76076847742355e-16f;
    p = __fadd_rn(__fmul_rn(p, x2), 2.00018790482477e-13f);
    p = __fadd_rn(__fmul_rn(p, x2), -8.60467152213735e-11f);
    p = __fadd_rn(__fmul_rn(p, x2), 5.12229709037114e-08f);
    p = __fadd_rn(__fmul_rn(p, x2), 1.48572235717979e-05f);
    p = __fadd_rn(__fmul_rn(p, x2), 6.37261928875436e-04f);
    p = __fadd_rn(__fmul_rn(p, x2), 4.89352455891786e-03f);
    float num = __fmul_rn(xc, p);
    float q = 1.19825839466702e-06f;
    q = __fadd_rn(__fmul_rn(q, x2), 1.18534705686654e-04f);
    q = __fadd_rn(__fmul_rn(q, x2), 2.26843463243900e-03f);
    q = __fadd_rn(__fmul_rn(q, x2), 4.89352518554385e-03f);
    float r = __fdiv_rn(num, q);
    return (fabsf(x) < 0.0004f) ? x : r;
}

__device__ __forceinline__ float gelu_exact(float xx) {
    float a = __fmul_rn(0.044715f, xx);
    a = __fmul_rn(a, xx);
    a = __fmul_rn(a, xx);
    float inner = __fadd_rn(xx, a);
    float tg = tanh_xla(__fmul_rn(0.7978845608028654f, inner));
    return __fmul_rn(__fmul_rn(0.5f, xx), __fadd_rn(1.0f, tg));
}

// ---------- fast-path helpers (loose tolerance) ----------
__device__ __forceinline__ float tanh_fast(float y) {
    float e = __builtin_amdgcn_exp2f(y * 2.8853900817779268f);
    return 1.0f - 2.0f * __builtin_amdgcn_rcpf(1.0f + e);
}

// per-pair elementwise: gelu, packed bins, cosine partials
__device__ __forceinline__ void elem2(
    v2f xx, v2f m, v2f iv, v2f mo, v2f io, v2f dv,
    float* ovp, uint32_t* bpp, v2f* aoo, v2f* aod)
{
    v2f x2 = xx * xx;
    v2f ax = xx * 0.044715f;
    v2f inner = __builtin_elementwise_fma(ax, x2, xx);
    v2f ea = inner * -2.3022269136469443f;   // -1.5957691 * log2(e)
    v2f ev; ev.x = __builtin_amdgcn_exp2f(ea.x);
    ev.y = __builtin_amdgcn_exp2f(ea.y);
    v2f dn = ev + 1.0f;
    v2f sg; sg.x = __builtin_amdgcn_rcpf(dn.x);
    sg.y = __builtin_amdgcn_rcpf(dn.y);
    v2f o2 = xx * sg;
    ovp[0] = o2.x; ovp[1] = o2.y;
    v2f zi = (xx - m) * iv;
    v2f zo = (o2 - mo) * io;
    v2f c511 = {511.0f, 511.0f};
    v2f bi = __builtin_elementwise_min(__builtin_elementwise_abs(zi) * 64.0f, c511);
    v2f bo = __builtin_elementwise_min(__builtin_elementwise_abs(zo) * 64.0f, c511);
    bpp[0] = (uint32_t)(int)bi.x | ((uint32_t)(int)bo.x << 16);
    bpp[1] = (uint32_t)(int)bi.y | ((uint32_t)(int)bo.y << 16);
    *aoo = __builtin_elementwise_fma(o2, o2, *aoo);
    *aod = __builtin_elementwise_fma(o2, dv, *aod);
}

// ---------- pre-kernel: denominators + ||dir||^2 + scalar params ----------
__global__ __launch_bounds__(BLK) void prep_kernel(
    const float* __restrict__ m_in, const float* __restrict__ q_in,
    const float* __restrict__ m_out, const float* __restrict__ q_out,
    const float* __restrict__ dirv,
    const float* __restrict__ p_log_tau,
    const float* __restrict__ p_log_beta,
    const float* __restrict__ p_log_gamma,
    float* __restrict__ wsp)
{
    __shared__ float spart[4];
    const int t = threadIdx.x;
    const int c = blockIdx.x * BLK + t;
    if (c < D_) {
        float mi = m_in[c];
        float vi = fmaxf(__fsub_rn(q_in[c], __fmul_rn(mi, mi)), 1e-4f);
        float di = __fadd_rn(__fsqrt_rn(vi), 1e-5f);
        wsp[c]        = di;                       // den_in
        wsp[D_ + c]   = __fdiv_rn(1.0f, di);      // inv_in
        float mo = m_out[c];
        float vo = fmaxf(__fsub_rn(q_out[c], __fmul_rn(mo, mo)), 1e-4f);
        float dd = __fadd_rn(__fsqrt_rn(vo), 1e-5f);
        wsp[2 * D_ + c] = dd;                     // den_out
        wsp[3 * D_ + c] = __fdiv_rn(1.0f, dd);    // inv_out
    }
    if (blockIdx.x == 0) {
        float acc = 0.f;
        #pragma unroll
        for (int k = 0; k < D_ / BLK; ++k) {
            float v = dirv[t + k * BLK];
            acc = fmaf(v, v, acc);
        }
        #pragma unroll
        for (int off = 32; off > 0; off >>= 1) acc += __shfl_xor(acc, off);
        if ((t & 63) == 0) spart[t >> 6] = acc;
        __syncthreads();
        if (t == 0) {
            wsp[4 * D_ + 0] = spart[0] + spart[1] + spart[2] + spart[3]; // ||dir||^2
            wsp[4 * D_ + 1] = expf(p_log_tau[0]);                        // tau
            wsp[4 * D_ + 2] = log1pf(expf(p_log_beta[0]));               // beta
            wsp[4 * D_ + 3] = log1pf(expf(p_log_gamma[0]));              // gamma
        }
    }
}

// suffix scan + boundary find over one 512-bin hist (one wave)
__device__ __forceinline__ void scan_one(
    const uint32_t* hp, volatile uint32_t* scr2, int lane)
{
    uint32_t h[8];
    *(uint4*)&h[0] = *(const uint4*)&hp[lane * 8 + 0];
    *(uint4*)&h[4] = *(const uint4*)&hp[lane * 8 + 4];
    uint32_t tot = 0;
    #pragma unroll
    for (int k = 0; k < 8; ++k) tot += h[k];
    uint32_t S = tot;
    #pragma unroll
    for (int d = 1; d < 64; d <<= 1) {
        uint32_t o = __shfl_down(S, d, 64);
        S += (lane + d < 64) ? o : 0u;
    }
    uint32_t run = S - tot;   // suffix strictly after this lane's bins
    #pragma unroll
    for (int k = 7; k >= 0; --k) {
        uint32_t prev = run;
        run += h[k];
        if (run >= (uint32_t)KSEL && prev < (uint32_t)KSEL) {
            scr2[0] = (uint32_t)(lane * 8 + k);  // B
            scr2[1] = prev;                      // G (count strictly above B)
        }
    }
}

__device__ __forceinline__ bool sel_one(
    uint32_t bin, int B, const uint32_t* ci, const uint32_t* cf,
    int nc, uint32_t ch)
{
    if ((int)bin > B) return true;
    if ((int)bin != B) return false;
    for (int jj = 0; jj < nc; ++jj)
        if (ci[jj] == ch) return cf[jj] != 0u;
    return false;
}

// ---------- main kernel: one block per TWO rows ----------
__global__ __launch_bounds__(BLK) void gelu205_kernel(
    const float* __restrict__ x,
    const float* __restrict__ ema_mean,
    const float* __restrict__ ema_out_mean,
    const float* __restrict__ ema_out_dir,
    const float* __restrict__ wsp,
    float* __restrict__ out,
    int nrows)
{
    // hist: 4 lists x 512 bins; cand lists: 4 x (cb,ci,cf x CAP); scr: 16
    __shared__ uint32_t lds[2048 + 4 * 3 * CAP + 16];
    uint32_t* hist = lds;                       // list L at hist + L*NBIN
    uint32_t* scr  = lds + 2048 + 4 * 3 * CAP;  // [2L]=B_L,[2L+1]=G_L, [8+L]=nc_L

    const int t = threadIdx.x;
    const int lane = t & 63, wid = t >> 6;
    const int r0 = blockIdx.x * 2, r1 = r0 + 1;
    const bool has2 = (r1 < nrows);

    const float* xr0 = x + (size_t)r0 * D_;
    const float* xr1 = x + (size_t)r1 * D_;
    float* outr0 = out + (size_t)r0 * D_;
    float* outr1 = out + (size_t)r1 * D_;

    const float* den_in  = wsp;
    const float* inv_in  = wsp + D_;
    const float* den_out = wsp + 2 * D_;
    const float* inv_out = wsp + 3 * D_;
    const float dd_row = wsp[4 * D_ + 0];
    const float tau    = wsp[4 * D_ + 1];
    const float beta   = wsp[4 * D_ + 2];
    const float gamma  = wsp[4 * D_ + 3];

    // zero hists (8 dwords/thread) + scr
    {
        uint4 z4 = make_uint4(0u, 0u, 0u, 0u);
        *(uint4*)&hist[t * 8 + 0] = z4;
        *(uint4*)&hist[t * 8 + 4] = z4;
    }
    if (t < 12) scr[t] = (t < 8 && (t & 1) == 0) ? 0xffffffffu : 0u;

    // ---- elementwise pass: 8 elems/thread/row, tables loaded once ----
    float ov0[8], ov1[8];
    uint32_t bp0[8], bp1[8];
    v2f aoo0 = {0.f, 0.f}, aod0 = {0.f, 0.f};
    v2f aoo1 = {0.f, 0.f}, aod1 = {0.f, 0.f};

    #pragma unroll
    for (int g = 0; g < 2; ++g) {
        const int base = (g << 10) + (t << 2);
        float4 m4  = *(const float4*)(ema_mean + base);
        float4 i4  = *(const float4*)(inv_in + base);
        float4 mo4 = *(const float4*)(ema_out_mean + base);
        float4 io4 = *(const float4*)(inv_out + base);
        float4 d4  = *(const float4*)(ema_out_dir + base);
        float4 xa  = *(const float4*)(xr0 + base);
        float4 xb;
        if (has2) xb = *(const float4*)(xr1 + base);
        else xb = make_float4(0.f, 0.f, 0.f, 0.f);
        const v2f* mp2  = (const v2f*)&m4;
        const v2f* ip2  = (const v2f*)&i4;
        const v2f* mop2 = (const v2f*)&mo4;
        const v2f* iop2 = (const v2f*)&io4;
        const v2f* dp2  = (const v2f*)&d4;
        const v2f* xa2  = (const v2f*)&xa;
        const v2f* xb2  = (const v2f*)&xb;
        #pragma unroll
        for (int p = 0; p < 2; ++p) {
            const int j = g * 4 + p * 2;
            elem2(xa2[p], mp2[p], ip2[p], mop2[p], iop2[p], dp2[p],
                  &ov0[j], &bp0[j], &aoo0, &aod0);
            elem2(xb2[p], mp2[p], ip2[p], mop2[p], iop2[p], dp2[p],
                  &ov1[j], &bp1[j], &aoo1, &aod1);
        }
    }

    // ---- cosine gates: wave shuffle reduce (all lanes get result) ----
    float oo0 = aoo0.x + aoo0.y, od0 = aod0.x + aod0.y;
    float oo1 = aoo1.x + aoo1.y, od1 = aod1.x + aod1.y;
    #pragma unroll
    for (int off = 32; off > 0; off >>= 1) {
        oo0 += __shfl_xor(oo0, off);
        od0 += __shfl_xor(od0, off);
        oo1 += __shfl_xor(oo1, off);
        od1 += __shfl_xor(od1, off);
    }
    // cross-wave combine via LDS (4 partials per row)
    __shared__ float sred[16];
    if (lane == 0) {
        sred[wid * 4 + 0] = oo0;
        sred[wid * 4 + 1] = od0;
        sred[wid * 4 + 2] = oo1;
        sred[wid * 4 + 3] = od1;
    }
    __syncthreads();                                    // B1 (also covers hist zero)

    float gcos0, gcos1;
    {
        float foo0 = sred[0] + sred[4] + sred[8] + sred[12];
        float fod0 = sred[1] + sred[5] + sred[9] + sred[13];
        float foo1 = sred[2] + sred[6] + sred[10] + sred[14];
        float fod1 = sred[3] + sred[7] + sred[11] + sred[15];
        float nd = fmaxf(sqrtf(dd_row), 1e-12f);
        float no0 = fmaxf(sqrtf(foo0), 1e-12f);
        float cs0 = fminf(fmaxf(fod0 / (no0 * nd), -1.0f), 1.0f);
        gcos0 = expf(-tau * cs0);
        float no1 = fmaxf(sqrtf(foo1), 1e-12f);
        float cs1 = fminf(fmaxf(fod1 / (no1 * nd), -1.0f), 1.0f);
        gcos1 = expf(-tau * cs1);
    }

    // ---- gated histograms ----
    #pragma unroll
    for (int j = 0; j < 8; ++j) {
        uint32_t bi = bp0[j] & 0xffffu, bo = bp0[j] >> 16;
        if (bi >= (uint32_t)B0) atomicAdd(&hist[bi], 1u);
        if (bo >= (uint32_t)B0) atomicAdd(&hist[NBIN + bo], 1u);
    }
    if (has2) {
        #pragma unroll
        for (int j = 0; j < 8; ++j) {
            uint32_t bi = bp1[j] & 0xffffu, bo = bp1[j] >> 16;
            if (bi >= (uint32_t)B0) atomicAdd(&hist[2 * NBIN + bi], 1u);
            if (bo >= (uint32_t)B0) atomicAdd(&hist[3 * NBIN + bo], 1u);
        }
    }
    __syncthreads();                                    // B2

    // ---- scan: wave w handles list w ----
    scan_one(hist + wid * NBIN, scr + 2 * wid, lane);
    __syncthreads();                                    // B3

    int BI0 = (int)scr[0], BO0 = (int)scr[2];
    int BI1 = (int)scr[4], BO1 = (int)scr[6];

    // uniform fallback: some list had < KSEL above the gate
    bool fb = (BI0 < 0) | (BO0 < 0) | (has2 & ((BI1 < 0) | (BO1 < 0)));
    if (fb) {
        #pragma unroll
        for (int j = 0; j < 8; ++j) {
            uint32_t bi = bp0[j] & 0xffffu, bo = bp0[j] >> 16;
            if (BI0 < 0 && bi < (uint32_t)B0) atomicAdd(&hist[bi], 1u);
            if (BO0 < 0 && bo < (uint32_t)B0) atomicAdd(&hist[NBIN + bo], 1u);
        }
        if (has2) {
            #pragma unroll
            for (int j = 0; j < 8; ++j) {
                uint32_t bi = bp1[j] & 0xffffu, bo = bp1[j] >> 16;
                if (BI1 < 0 && bi < (uint32_t)B0) atomicAdd(&hist[2 * NBIN + bi], 1u);
                if (BO1 < 0 && bo < (uint32_t)B0) atomicAdd(&hist[3 * NBIN + bo], 1u);
            }
        }
        __syncthreads();
        scan_one(hist + wid * NBIN, scr + 2 * wid, lane);
        __syncthreads();
        BI0 = (int)scr[0]; BO0 = (int)scr[2];
        BI1 = (int)scr[4]; BO1 = (int)scr[6];
    }

    // ---- boundary-candidate gather; owners recompute EXACT values ----
    uint32_t* cb0 = lds + 2048;              // list 0 = row0 IN
    uint32_t* cb1 = cb0 + 3 * CAP;           // list 1 = row0 OUT
    uint32_t* cb2 = cb1 + 3 * CAP;           // list 2 = row1 IN
    uint32_t* cb3 = cb2 + 3 * CAP;           // list 3 = row1 OUT

    #pragma unroll
    for (int j = 0; j < 8; ++j) {
        const int ch = ((j >> 2) << 10) + (t << 2) + (j & 3);
        if ((int)(bp0[j] & 0xffffu) == BI0) {
            float xx = xr0[ch];
            float ze = fabsf(__fdiv_rn(__fsub_rn(xx, ema_mean[ch]), den_in[ch]));
            uint32_t sl = atomicAdd(&scr[8], 1u);
            if (sl < CAP) { cb0[sl] = __float_as_uint(ze); cb0[CAP + sl] = (uint32_t)ch; }
        }
        if ((int)(bp0[j] >> 16) == BO0) {
            float xx = xr0[ch];
            float oe = gelu_exact(xx);
            float ze = fabsf(__fdiv_rn(__fsub_rn(oe, ema_out_mean[ch]), den_out[ch]));
            uint32_t sl = atomicAdd(&scr[9], 1u);
            if (sl < CAP) { cb1[sl] = __float_as_uint(ze); cb1[CAP + sl] = (uint32_t)ch; }
        }
        if (has2) {
            if ((int)(bp1[j] & 0xffffu) == BI1) {
                float xx = xr1[ch];
                float ze = fabsf(__fdiv_rn(__fsub_rn(xx, ema_mean[ch]), den_in[ch]));
                uint32_t sl = atomicAdd(&scr[10], 1u);
                if (sl < CAP) { cb2[sl] = __float_as_uint(ze); cb2[CAP + sl] = (uint32_t)ch; }
            }
            if ((int)(bp1[j] >> 16) == BO1) {
                float xx = xr1[ch];
                float oe = gelu_exact(xx);
                float ze = fabsf(__fdiv_rn(__fsub_rn(oe, ema_out_mean[ch]), den_out[ch]));
                uint32_t sl = atomicAdd(&scr[11], 1u);
                if (sl < CAP) { cb3[sl] = __float_as_uint(ze); cb3[CAP + sl] = (uint32_t)ch; }
            }
        }
    }
    __syncthreads();                                    // B4

    // ---- exact rank among candidates: wave w ranks list w ----
    {
        uint32_t* cbw = lds + 2048 + wid * 3 * CAP;
        int Bw = (int)scr[2 * wid];
        if (Bw >= 0) {
            const int nc = min((int)scr[8 + wid], CAP);
            const uint32_t need = (uint32_t)(KSEL - (int)scr[2 * wid + 1]);
            for (int i = lane; i < nc; i += 64) {
                uint32_t ui = cbw[i], di = cbw[CAP + i], r = 0;
                for (int jj = 0; jj < nc; ++jj) {
                    uint32_t uj = cbw[jj];
                    r += (uj > ui || (uj == ui && cbw[CAP + jj] < di)) ? 1u : 0u;
                }
                cbw[2 * CAP + i] = (r < need) ? 1u : 0u;
            }
        }
    }
    __syncthreads();                                    // B5

    const int nc0 = min((int)scr[8], CAP),  nc1 = min((int)scr[9], CAP);
    const int nc2 = min((int)scr[10], CAP), nc3 = min((int)scr[11], CAP);

    // ---- epilogue: lazy gate + write ----
    #pragma unroll
    for (int k = 0; k < 2; ++k) {
        float4 r4;
        float* rp = (float*)&r4;
        #pragma unroll
        for (int l = 0; l < 4; ++l) {
            const int j = k * 4 + l;
            const uint32_t ch = (uint32_t)(((j >> 2) << 10) + (t << 2) + (j & 3));
            bool selI = sel_one(bp0[j] & 0xffffu, BI0, cb0 + CAP, cb0 + 2 * CAP, nc0, ch);
            bool selO = sel_one(bp0[j] >> 16,     BO0, cb1 + CAP, cb1 + 2 * CAP, nc1, ch);
            float gate = 1.0f;
            if (selI && selO) {
                float xx = xr0[ch];
                float zi = (xx - ema_mean[ch]) * inv_in[ch];
                float th = tanh_fast(gamma * zi);
                gate = fminf(fmaxf(fmaf(beta, th, 1.0f), 0.1f), 8.0f);
            }
            rp[l] = ov0[j] * gate * gcos0;
        }
        *(float4*)(outr0 + (k << 10) + (t << 2)) = r4;
    }
    if (has2) {
        #pragma unroll
        for (int k = 0; k < 2; ++k) {
            float4 r4;
            float* rp = (float*)&r4;
            #pragma unroll
            for (int l = 0; l < 4; ++l) {
                const int j = k * 4 + l;
                const uint32_t ch = (uint32_t)(((j >> 2) << 10) + (t << 2) + (j & 3));
                bool selI = sel_one(bp1[j] & 0xffffu, BI1, cb2 + CAP, cb2 + 2 * CAP, nc2, ch);
                bool selO = sel_one(bp1[j] >> 16,     BO1, cb3 + CAP, cb3 + 2 * CAP, nc3, ch);
                float gate = 1.0f;
                if (selI && selO) {
                    float xx = xr1[ch];
                    float zi = (xx - ema_mean[ch]) * inv_in[ch];
                    float th = tanh_fast(gamma * zi);
                    gate = fminf(fmaxf(fmaf(beta, th, 1.0f), 0.1f), 8.0f);
                }
                rp[l] = ov1[j] * gate * gcos1;
            }
            *(float4*)(outr1 + (k << 10) + (t << 2)) = r4;
        }
    }
}

extern "C" void kernel_launch(void* const* d_in, const int* in_sizes, int n_in,
                              void* d_out, int out_size, void* d_ws, size_t ws_size,
                              hipStream_t stream) {
    const float* x            = (const float*)d_in[0];
    const float* p_log_tau    = (const float*)d_in[2];
    const float* p_log_beta   = (const float*)d_in[3];
    const float* p_log_gamma  = (const float*)d_in[4];
    const float* ema_mean     = (const float*)d_in[5];
    const float* ema_sq       = (const float*)d_in[6];
    const float* ema_out_mean = (const float*)d_in[7];
    const float* ema_out_sq   = (const float*)d_in[8];
    const float* ema_out_dir  = (const float*)d_in[9];
    float* wsp = (float*)d_ws;
    const int rows = in_sizes[0] / D_;

    prep_kernel<<<(D_ + BLK - 1) / BLK, BLK, 0, stream>>>(
        ema_mean, ema_sq, ema_out_mean, ema_out_sq, ema_out_dir,
        p_log_tau, p_log_beta, p_log_gamma, wsp);
    gelu205_kernel<<<(rows + 1) / 2, BLK, 0, stream>>>(
        x, ema_mean, ema_out_mean, ema_out_dir, wsp,
        (float*)d_out, rows);
}